// Round 7
// baseline (3114.528 us; speedup 1.0000x reference)
//
#include <hip/hip_runtime.h>

#define Bq 64
#define Sq 32
#define VFq 512
#define IFq 256
#define Fq 768
#define Uq 768
#define UNFq 6
#define L2E 1.44269504088896340736f

template <int CTRL>
__device__ __forceinline__ float dpp_add(float x) {
  int t = __builtin_amdgcn_update_dpp(0, __builtin_bit_cast(int, x), CTRL, 0xF, 0xF, true);
  return x + __builtin_bit_cast(float, t);
}
__device__ __forceinline__ float swz_add4(float x) {
  int t = __builtin_amdgcn_ds_swizzle(__builtin_bit_cast(int, x), 0x101F); // xor 4
  return x + __builtin_bit_cast(float, t);
}

// ---------------- K1: fold+transpose params, init misc ----------------
// P[u][v] = float4(-sigma*log2e, sigma*mu*log2e, w, w*erev)  (u = target, v = source)
__global__ __launch_bounds__(256) void k_prep(
    const float* __restrict__ smu, const float* __restrict__ ssig,
    const float* __restrict__ sw,  const float* __restrict__ ser,
    const float* __restrict__ rmu, const float* __restrict__ rsig,
    const float* __restrict__ rw,  const float* __restrict__ rer,
    const float* __restrict__ ts,
    float4* __restrict__ Ps, float4* __restrict__ Pr,
    float* __restrict__ iel, unsigned* __restrict__ flags)
{
  int bid = blockIdx.x, tid = threadIdx.x;
  if (bid < 1152) {
    int set = bid / 576, tile = bid % 576;
    int tv = tile / 24, tu = tile % 24;
    const float* Amu = set ? rmu : smu;
    const float* Asg = set ? rsig : ssig;
    const float* Aw  = set ? rw  : sw;
    const float* Aer = set ? rer : ser;
    float4* P = set ? Pr : Ps;
    __shared__ float4 tl[32][33];
    int cu = tid & 31, r0 = tid >> 5;            // 32 cols x 8 rows
    for (int rr = 0; rr < 32; rr += 8) {
      int v = tv*32 + r0 + rr, u = tu*32 + cu;
      int idx = v*Uq + u;                         // source-major input layout
      float sg = Asg[idx], m = Amu[idx], ww = Aw[idx], er = Aer[idx];
      tl[cu][r0+rr] = make_float4(-sg*L2E, sg*m*L2E, ww, ww*er); // transposed in LDS
    }
    __syncthreads();
    for (int rr = 0; rr < 32; rr += 8) {
      int u = tu*32 + r0 + rr, v = tv*32 + (tid & 31);
      P[u*Fq + v] = tl[r0+rr][tid & 31];          // coalesced write, [u][v]
    }
  } else {
    for (int i = tid; i < Bq*Sq; i += 256) {
      int b = i / Sq, t = i % Sq;
      iel[i] = (float)UNFq / (ts[b*(Sq+1)+t+1] - ts[b*(Sq+1)+t]); // 6/elapsed
    }
    for (int i = tid; i < 1024; i += 256) flags[i] = 0u;  // per-block phase flags
  }
}

// ---------------- K2: sensory synapse sums for all (b,t) ----------------
// (plain rcp here: x ~ N(0,1) can push the paired-product to overflow)
__global__ __launch_bounds__(768) void k_sensory(
    const float* __restrict__ fv, const float* __restrict__ fi,
    const float* __restrict__ iw, const float* __restrict__ ib,
    const float4* __restrict__ Ps,
    float* __restrict__ wns, float* __restrict__ wds)
{
  __shared__ float xs[16][Fq];
  __shared__ float scr[12][8][33];
  int tid = threadIdx.x;
  int bt_tile = blockIdx.x >> 6;                  // 128 tiles of 16 (b,t)
  int ut = blockIdx.x & 63;                       // 64 u-tiles of 12
  int u0 = ut * 12, bt0 = bt_tile * 16;
  {
    float wv = iw[tid], bv = ib[tid];
    for (int j = 0; j < 16; ++j) {
      int bt = bt0 + j, b = bt >> 5, t = bt & 31;
      float raw = (tid < VFq) ? fv[(b*Sq + t)*VFq + tid]
                              : fi[(b*Sq + t)*IFq + (tid - VFq)];
      xs[j][tid] = raw * wv + bv;
    }
  }
  __syncthreads();
  int w = tid >> 6, l = tid & 63;
  const float4* P = Ps + (u0 + w)*Fq;
  #pragma unroll
  for (int pass = 0; pass < 4; ++pass) {
    float num[4], den[4];
    #pragma unroll
    for (int q = 0; q < 4; ++q) { num[q] = 0.f; den[q] = 0.f; }
    for (int i = 0; i < 12; ++i) {
      int f = l + 64*i;
      float4 p = P[f];
      #pragma unroll
      for (int q = 0; q < 4; ++q) {
        float arg = fmaf(p.x, xs[4*pass + q][f], p.y);
        float e = __builtin_amdgcn_exp2f(arg);
        float r = __builtin_amdgcn_rcpf(1.0f + e);  // sigmoid
        den[q] = fmaf(p.z, r, den[q]);
        num[q] = fmaf(p.w, r, num[q]);
      }
    }
    #pragma unroll
    for (int q = 0; q < 4; ++q) {
      num[q] = dpp_add<0xB1>(num[q]); den[q] = dpp_add<0xB1>(den[q]);
      num[q] = dpp_add<0x4E>(num[q]); den[q] = dpp_add<0x4E>(den[q]);
      num[q] = swz_add4(num[q]);      den[q] = swz_add4(den[q]);
    }
    if ((l & 7) == 0) {
      int rep = l >> 3;
      #pragma unroll
      for (int q = 0; q < 4; ++q) {
        scr[w][rep][4*pass + q] = num[q];
        scr[w][rep][16 + 4*pass + q] = den[q];
      }
    }
    __builtin_amdgcn_sched_barrier(0);
  }
  __syncthreads();
  if (tid < 192) {
    int u = tid >> 4, j = tid & 15;
    float nt = 0.f, dt = 0.f;
    #pragma unroll
    for (int rep = 0; rep < 8; ++rep) { nt += scr[u][rep][j]; dt += scr[u][rep][16+j]; }
    int bt = bt0 + j, b = bt >> 5, t = bt & 31;
    wns[(t*Bq + b)*Uq + (u0 + u)] = nt;
    wds[(t*Bq + b)*Uq + (u0 + u)] = dt;
  }
}

// ---------------- K3: recurrent unfolds (persistent, 2 blocks/CU) ----------------
// 512 blocks = 8 groups(8 b) x 64 u-tiles(12 u); 2 blocks co-resident per CU
// (24 waves/CU: one block's compute hides the other's barrier wait, and trans/
// VALU pipes interleave across more waves — R6's 12 waves left VALUBusy at 61%
// with poor trans/VALU overlap). Wave w <-> target u = u0+w, full 768-v row in
// 48 VGPRs. Halves of 4 j pipeline the barrier RTT intra-block as before.
// Paired reciprocal: 2 sigmoids share one v_rcp (trans 9216->6912 cyc/SIMD/ph;
// safe: |v|<~1.2, sigma<=8 -> pair product <= 2^50).
// VGPR budget 84 (24 waves/CU target). If this ever exceeds 84 the grid stops
// being co-resident and the kernel DEADLOCKS — keep the live set small.
__global__ __launch_bounds__(768)
void k_recurrent(
    const float4* __restrict__ Pr,
    const float* __restrict__ wns, const float* __restrict__ wds,
    float* __restrict__ vg, const float* __restrict__ iel,
    unsigned* __restrict__ flags,
    const float* __restrict__ gleak, const float* __restrict__ vleak,
    const float* __restrict__ cm, const float* __restrict__ ow,
    const float* __restrict__ ob, float* __restrict__ hout)
{
  __shared__ float4 vvP[2][Uq];         // 24 KiB: panel h = 4 j's of half h
  __shared__ float2 scr2[12][8][5];     // 3.75 KiB cross-lane reduce scratch
  __shared__ float sinv[8][Sq];         // 1 KiB
  __shared__ float swn[2][48], swd[2][48];
  __shared__ float sgl[12], sglvl[12], scm[12], sow[12], sob[12];
  int tid = threadIdx.x;
  int g = blockIdx.x >> 6;              // group 0..7 (8 batches each)
  int ut = blockIdx.x & 63;             // u-tile 0..63
  int u0 = ut*12, b0 = g*8;
  if (tid < 256) { int j = tid >> 5, t = tid & 31; sinv[j][t] = iel[(b0+j)*Sq + t]; }
  if (tid < 12) {
    float gl0 = gleak[u0+tid];
    sgl[tid] = gl0; sglvl[tid] = gl0 * vleak[u0+tid];
    scm[tid] = cm[u0+tid]; sow[tid] = ow[u0+tid]; sob[tid] = ob[u0+tid];
  }
  vvP[0][tid] = make_float4(0.f, 0.f, 0.f, 0.f);
  vvP[1][tid] = make_float4(0.f, 0.f, 0.f, 0.f);
  int w = tid >> 6, l = tid & 63;
  float4 Prg[12];                       // entire P-row slice in registers (48 VGPRs)
  #pragma unroll
  for (int i = 0; i < 12; ++i) Prg[i] = Pr[(u0 + w)*Uq + l + 64*i];
  __syncthreads();
  int uu = tid >> 2, jv = tid & 3;      // tail mapping (tid<48)
  int p = 1;                            // phase 1..192
  for (int t = 0; t < Sq; ++t) {
    if (tid < 48) {                     // stash this t's sensory sums in LDS
      swn[0][tid] = wns[(t*Bq + b0 + jv)*Uq + u0 + uu];
      swd[0][tid] = wds[(t*Bq + b0 + jv)*Uq + u0 + uu];
      swn[1][tid] = wns[(t*Bq + b0 + 4 + jv)*Uq + u0 + uu];
      swd[1][tid] = wds[(t*Bq + b0 + 4 + jv)*Uq + u0 + uu];
    }
    for (int k = 0; k < UNFq; ++k, ++p) {
      int sp = p & 1, rp = sp ^ 1;      // store parity / reload parity
      #pragma unroll
      for (int h = 0; h < 2; ++h) {
        // ---- wait peers' half-h state(p-1), gather into panel ----
        if (p > 1) {
          const unsigned* f = flags + (h*8 + g)*64 + l;   // every wave polls
          unsigned tgt = (unsigned)(p - 1);
          while (true) {
            unsigned vf = __hip_atomic_load(f, __ATOMIC_RELAXED, __HIP_MEMORY_SCOPE_AGENT);
            if (__ballot(vf < tgt) == 0ull) break;
            __builtin_amdgcn_s_sleep(1);
          }
          const unsigned long long* src = (const unsigned long long*)
              (vg + (((rp*2 + h)*8 + g)*Uq + tid)*4);
          unsigned long long q0 = __hip_atomic_load(src + 0, __ATOMIC_RELAXED,
                                                    __HIP_MEMORY_SCOPE_AGENT);
          unsigned long long q1 = __hip_atomic_load(src + 1, __ATOMIC_RELAXED,
                                                    __HIP_MEMORY_SCOPE_AGENT);
          float2 t0 = __builtin_bit_cast(float2, q0);
          float2 t1 = __builtin_bit_cast(float2, q1);
          vvP[h][tid] = make_float4(t0.x, t0.y, t1.x, t1.y);
        }
        __syncthreads();                // panel ready (or initial zeros)
        // ---- compute half h (4 j), paired-rcp sigmoid ----
        {
          float num[4], den[4];
          #pragma unroll
          for (int q = 0; q < 4; ++q) { num[q] = 0.f; den[q] = 0.f; }
          #pragma unroll
          for (int i = 0; i < 12; ++i) {
            int v = l + 64*i;
            float4 pp = Prg[i];
            float4 y = vvP[h][v];       // ds_read_b128
            float e0 = 1.0f + __builtin_amdgcn_exp2f(fmaf(pp.x, y.x, pp.y));
            float e1 = 1.0f + __builtin_amdgcn_exp2f(fmaf(pp.x, y.y, pp.y));
            float e2 = 1.0f + __builtin_amdgcn_exp2f(fmaf(pp.x, y.z, pp.y));
            float e3 = 1.0f + __builtin_amdgcn_exp2f(fmaf(pp.x, y.w, pp.y));
            float r01 = __builtin_amdgcn_rcpf(e0 * e1);
            float r23 = __builtin_amdgcn_rcpf(e2 * e3);
            float s0 = r01 * e1, s1 = r01 * e0;   // 1/e0, 1/e1
            float s2 = r23 * e3, s3 = r23 * e2;
            den[0] = fmaf(pp.z, s0, den[0]);
            num[0] = fmaf(pp.w, s0, num[0]);
            den[1] = fmaf(pp.z, s1, den[1]);
            num[1] = fmaf(pp.w, s1, num[1]);
            den[2] = fmaf(pp.z, s2, den[2]);
            num[2] = fmaf(pp.w, s2, num[2]);
            den[3] = fmaf(pp.z, s3, den[3]);
            num[3] = fmaf(pp.w, s3, num[3]);
          }
          #pragma unroll
          for (int q = 0; q < 4; ++q) {
            num[q] = dpp_add<0xB1>(num[q]); den[q] = dpp_add<0xB1>(den[q]);
            num[q] = dpp_add<0x4E>(num[q]); den[q] = dpp_add<0x4E>(den[q]);
            num[q] = swz_add4(num[q]);      den[q] = swz_add4(den[q]);
          }
          if ((l & 7) == 0) {
            int r = l >> 3;
            #pragma unroll
            for (int q = 0; q < 4; ++q)
              scr2[w][r][q] = make_float2(num[q], den[q]);
          }
          __builtin_amdgcn_sched_barrier(0);  // cap register pressure
        }
        __syncthreads();
        // ---- tail: finish reduction + ODE step for (12u x 4j) ----
        if (tid < 48) {
          float nt = swn[h][tid], dt = swd[h][tid];
          #pragma unroll
          for (int r = 0; r < 8; ++r) { float2 s = scr2[uu][r][jv]; nt += s.x; dt += s.y; }
          int jh = h*4 + jv;
          float cmt = scm[uu] * sinv[jh][t];
          const float* vrow = (const float*)&vvP[h][u0 + uu];
          float vold = vrow[jv];
          float vnew = (cmt*vold + sglvl[uu] + nt)
                     * __builtin_amdgcn_rcpf(cmt + sgl[uu] + dt + 1e-8f);
          __hip_atomic_store(&vg[(((sp*2 + h)*8 + g)*Uq + u0 + uu)*4 + jv], vnew,
                             __ATOMIC_RELAXED, __HIP_MEMORY_SCOPE_AGENT);
          if (k == UNFq-1)
            hout[((b0 + jh)*Sq + t)*Uq + u0 + uu] = fmaf(vnew, sow[uu], sob[uu]);
        }
        __builtin_amdgcn_s_waitcnt(0);  // each wave drains its stores
        __syncthreads();                // tail stores globally visible
        if (tid == 0)                   // contention-free signal (plain store)
          __hip_atomic_store(&flags[(h*8 + g)*64 + ut], (unsigned)p,
                             __ATOMIC_RELAXED, __HIP_MEMORY_SCOPE_AGENT);
      }
    }
  }
}

// ---------------- K4: regressor head ----------------
__global__ __launch_bounds__(128) void k_head(
    const float* __restrict__ hseq, const float* __restrict__ W1,
    const float* __restrict__ b1, const float* __restrict__ W2,
    const float* __restrict__ b2, float* __restrict__ pose)
{
  __shared__ float h[Uq];
  __shared__ float x1[128];
  int bt = blockIdx.x, tid = threadIdx.x;
  for (int j = 0; j < 6; ++j) h[tid + 128*j] = hseq[bt*Uq + tid + 128*j];
  __syncthreads();
  float acc = b1[tid];
  for (int f = 0; f < Uq; ++f) acc = fmaf(h[f], W1[f*128 + tid], acc);
  x1[tid] = acc > 0.f ? acc : 0.1f*acc;            // LeakyReLU(0.1); h0 == 0
  __syncthreads();
  if (tid < 6) {
    float a2 = b2[tid];
    #pragma unroll
    for (int c = 0; c < 128; ++c) a2 = fmaf(x1[c], W2[c*6 + tid], a2);
    pose[bt*6 + tid] = a2;
  }
}

extern "C" void kernel_launch(void* const* d_in, const int* in_sizes, int n_in,
                              void* d_out, int out_size, void* d_ws, size_t ws_size,
                              hipStream_t stream) {
  const float* fv   = (const float*)d_in[0];
  const float* fi   = (const float*)d_in[2];
  const float* ts   = (const float*)d_in[4];
  const float* iw   = (const float*)d_in[5];
  const float* ibb  = (const float*)d_in[6];
  const float* smu  = (const float*)d_in[7];
  const float* ssig = (const float*)d_in[8];
  const float* sw   = (const float*)d_in[9];
  const float* ser  = (const float*)d_in[10];
  const float* rmu  = (const float*)d_in[11];
  const float* rsig = (const float*)d_in[12];
  const float* rw   = (const float*)d_in[13];
  const float* rer  = (const float*)d_in[14];
  const float* gl   = (const float*)d_in[15];
  const float* vl   = (const float*)d_in[16];
  const float* cm   = (const float*)d_in[17];
  const float* ow   = (const float*)d_in[18];
  const float* ob   = (const float*)d_in[19];
  const float* W1   = (const float*)d_in[20];
  const float* b1   = (const float*)d_in[21];
  const float* W2   = (const float*)d_in[22];
  const float* b2   = (const float*)d_in[23];

  float* pose = (float*)d_out;                 // (B,1,S,6) = 12288 floats
  float* hseq = (float*)d_out + Bq*Sq*6;       // (B,S,U)   = 1572864 floats

  float* ws = (float*)d_ws;
  float4* Ps = (float4*)ws;                    // 2,359,296 floats
  float4* Pr = (float4*)(ws + 2359296);        // 2,359,296
  float* wns = ws + 4718592;                   // 1,572,864
  float* wds = ws + 6291456;                   // 1,572,864
  float* vg  = ws + 7864320;                   // 98,304 (2 par x 2 half x 8 g x 768 x 4)
  float* iel = ws + 7962624;                   // 2,048
  unsigned* flags = (unsigned*)(ws + 7964672); // 1,024 (2 half x 8 g x 64 blocks)

  k_prep<<<1153, 256, 0, stream>>>(smu, ssig, sw, ser, rmu, rsig, rw, rer,
                                   ts, Ps, Pr, iel, flags);
  k_sensory<<<8192, 768, 0, stream>>>(fv, fi, iw, ibb, Ps, wns, wds);
  k_recurrent<<<512, 768, 0, stream>>>(Pr, wns, wds, vg, iel, flags,
                                       gl, vl, cm, ow, ob, hseq);
  k_head<<<2048, 128, 0, stream>>>(hseq, W1, b1, W2, b2, pose);
}